// Round 3
// baseline (217.790 us; speedup 1.0000x reference)
//
#include <hip/hip_runtime.h>
#include <stdint.h>

typedef int v4i __attribute__((ext_vector_type(4)));

// Problem dims
#define N_IMG 32
#define C_IN 256
#define H_IN 56
#define W_IN 56
#define C_OUT 256
#define H_OUT 28
#define W_OUT 28
#define H_PAD 58
#define W_PAD 58
#define SP_TOT (N_IMG*H_OUT*W_OUT)   // 25088

#define XPAD_BYTES ((size_t)N_IMG*H_PAD*W_PAD*C_IN)   // 27,557,888 (16B aligned)
#define WQ_BYTES   ((size_t)9*C_OUT*C_IN)             // 589,824

__device__ __forceinline__ void glds16(const int8_t* g, int8_t* l) {
    __builtin_amdgcn_global_load_lds(
        (const __attribute__((address_space(1))) void*)g,
        (__attribute__((address_space(3))) void*)l, 16, 0, 0);
}

// ---------------------------------------------------------------------------
// Kernel 1: quantize fp32 NCHW -> int8 NHWC, zero-padding borders inline.
// Grid (N, 58). Interior rows: each thread quantizes 4 consecutive channels
// for one w and packs them into ONE u32 ds_write_b32 (no byte-granular LDS
// writes, no same-word collisions). LDS stride 65 u32: Phase A banks are
// consecutive (conflict-free), Phase B reads 2-way aliased (free).
// ---------------------------------------------------------------------------
__global__ __launch_bounds__(256) void quant_kernel(const float* __restrict__ x,
                                                    int8_t* __restrict__ xpad) {
    __shared__ uint32_t ldsu[W_IN * 65];           // 14,560 B
    const int n = blockIdx.x, hp = blockIdx.y;     // hp in [0,58)
    const int t = threadIdx.x;
    int8_t* row = xpad + ((size_t)n * H_PAD + hp) * W_PAD * C_IN;

    if (hp == 0 || hp == H_PAD - 1) {
        // zero full padded row: 58*256 B = 928 x 16B
        #pragma unroll
        for (int i = 0; i < 4; ++i) {
            int idx = i * 256 + t;
            if (idx < 928) *(int4*)(row + idx * 16) = (int4){0, 0, 0, 0};
        }
        return;
    }
    const int h = hp - 1;
    const float* xp = x + (size_t)n * C_IN * H_IN * W_IN + (size_t)h * W_IN;

    // Phase A: thread owns (c4, w); 4 coalesced dword loads, pack u32, 1 LDS write
    #pragma unroll
    for (int it = 0; it < 14; ++it) {           // 14*256 = 3584 = 64 c4 * 56 w
        int idx = it * 256 + t;
        int c4 = idx / 56, w = idx - c4 * 56;
        const float* p = xp + (size_t)(c4 * 4) * (H_IN * W_IN) + w;
        uint32_t u = 0;
        #pragma unroll
        for (int i = 0; i < 4; ++i) {
            float qv = rintf(p[(size_t)i * (H_IN * W_IN)] / 0.05f);  // IEEE div, half-even
            qv = fminf(fmaxf(qv, -128.0f), 127.0f);
            u |= ((uint32_t)((int)qv & 255)) << (8 * i);
        }
        ldsu[w * 65 + c4] = u;
    }
    // zero border pixels w_p = 0 and w_p = 57 (32 x 16B), disjoint from Phase B
    if (t < 32) {
        int8_t* p = (t < 16) ? (row + t * 16)
                             : (row + (size_t)(W_PAD - 1) * C_IN + (t - 16) * 16);
        *(int4*)p = (int4){0, 0, 0, 0};
    }
    __syncthreads();

    // Phase B: write x_pad[n][hp][w+1][c], 256B fully-coalesced per wave
    int8_t* op = row + C_IN;                    // w_p starts at 1
    #pragma unroll
    for (int it = 0; it < 14; ++it) {           // 56 w * 64 c4 = 3584
        int idx = it * 256 + t;
        int w = idx >> 6, c4 = idx & 63;
        *(uint32_t*)(op + (size_t)w * C_IN + c4 * 4) = ldsu[w * 65 + c4];
    }
}

// ---------------------------------------------------------------------------
// Kernel 2: repack weights fp32 [co][ci][kh][kw] -> int8 wq[khw][co][ci]
// ---------------------------------------------------------------------------
__global__ __launch_bounds__(256) void wq_kernel(const float* __restrict__ w,
                                                 int8_t* __restrict__ wq) {
    int idx = blockIdx.x * 256 + threadIdx.x;   // < 9*256*256 = 589824
    int ci  = idx & 255;
    int co  = (idx >> 8) & 255;
    int khw = idx >> 16;
    float v = w[(size_t)(co * C_IN + ci) * 9 + khw];
    wq[idx] = (int8_t)(int)rintf(v);
}

// ---------------------------------------------------------------------------
// Kernel 3: implicit-GEMM conv, LDS-staged (m97 structure). Unchanged from R1.
// Block 256 thr = 4 waves, tile 128co x 64sp; 9 stages (one 3x3 tap each,
// BK = 256 ci). Per stage: global_load_lds dwordx4 stages W(32KB)+Act(16KB)
// into LDS with XOR chunk swizzle; ds_read_b128 fragment reads conflict-free.
// 32 MFMA/wave between barriers.
// C/D: col(sp) = s, row(co) = q*4 + reg   [verified mapping]
// ---------------------------------------------------------------------------
__global__ __launch_bounds__(256) void conv_kernel(const int8_t* __restrict__ xpad,
                                                   const int8_t* __restrict__ wq,
                                                   float* __restrict__ out) {
    __shared__ __align__(16) int8_t lds[49152];  // W: [0,32768) Act: [32768,49152)
    const int t = threadIdx.x;
    const int wave = t >> 6, lane = t & 63;
    const int q = lane >> 4, s = lane & 15;
    const int co_blk = blockIdx.y * 128;
    const int sp_blk = blockIdx.x * 64;

    // ---- staging decode (fixed per thread) ----
    const int row_l4 = wave * 4 + q;                 // row_l mod 16
    const int chunk  = (lane & 15) ^ row_l4;
    const int8_t* gw = wq + (size_t)(co_blk + row_l4) * 256 + chunk * 16;

    const int8_t* ga[4];
    #pragma unroll
    for (int r = 0; r < 4; ++r) {
        int sp = sp_blk + r * 16 + row_l4;
        int n  = sp / (H_OUT * W_OUT);
        int rm = sp - n * (H_OUT * W_OUT);
        int ho = rm / W_OUT;
        int wo = rm - ho * W_OUT;
        ga[r] = xpad + ((size_t)(n * H_PAD + ho * 2) * W_PAD + wo * 2) * C_IN + chunk * 16;
    }

    int8_t* lw = lds + wave * 1024;           // + r*4096
    int8_t* la = lds + 32768 + wave * 1024;   // + r*4096

    // ---- output mapping ----
    const int cw = (wave >> 1) * 64;          // LDS-local co base of this wave
    const int sw = (wave & 1) * 32;           // LDS-local sp base of this wave
    int out_base[2];
    #pragma unroll
    for (int j = 0; j < 2; ++j) {
        int sp = sp_blk + sw + j * 16 + s;
        int n  = sp / (H_OUT * W_OUT);
        int rm = sp - n * (H_OUT * W_OUT);
        int ho = rm / W_OUT;
        int wo = rm - ho * W_OUT;
        out_base[j] = n * (C_OUT * H_OUT * W_OUT) + ho * W_OUT + wo;
    }

    v4i acc[4][2];
    #pragma unroll
    for (int i = 0; i < 4; ++i)
        #pragma unroll
        for (int j = 0; j < 2; ++j)
            acc[i][j] = (v4i){0, 0, 0, 0};

    // ---- K loop: 9 stages (one tap each) ----
    for (int kh = 0; kh < 3; ++kh) {
        for (int kwv = 0; kwv < 3; ++kwv) {
            __syncthreads();                       // all waves done reading prev stage
            const int woff = (kh * 3 + kwv) * (C_OUT * C_IN);
            const int aoff = (kh * W_PAD + kwv) * C_IN;
            #pragma unroll
            for (int r = 0; r < 8; ++r)
                glds16(gw + woff + r * 4096, lw + r * 4096);
            #pragma unroll
            for (int r = 0; r < 4; ++r)
                glds16(ga[r] + aoff, la + r * 4096);
            __syncthreads();                       // vmcnt(0) drain: LDS ready

            #pragma unroll
            for (int ks = 0; ks < 4; ++ks) {
                const int st = ((ks * 4 + q) ^ s) * 16;   // swizzled chunk offset
                v4i a[4], b[2];
                #pragma unroll
                for (int i = 0; i < 4; ++i)
                    a[i] = *(const v4i*)(lds + (cw + i * 16 + s) * 256 + st);
                #pragma unroll
                for (int j = 0; j < 2; ++j)
                    b[j] = *(const v4i*)(lds + 32768 + (sw + j * 16 + s) * 256 + st);
                #pragma unroll
                for (int i = 0; i < 4; ++i)
                    #pragma unroll
                    for (int j = 0; j < 2; ++j)
                        acc[i][j] = __builtin_amdgcn_mfma_i32_16x16x64_i8(
                            a[i], b[j], acc[i][j], 0, 0, 0);
            }
        }
    }

    // ---- epilogue ----
    #pragma unroll
    for (int j = 0; j < 2; ++j) {
        #pragma unroll
        for (int i = 0; i < 4; ++i) {
            const int co0 = co_blk + cw + i * 16 + q * 4;
            #pragma unroll
            for (int r = 0; r < 4; ++r) {
                out[(size_t)out_base[j] + (size_t)(co0 + r) * (H_OUT * W_OUT)] =
                    (float)acc[i][j][r] * 0.0005f;
            }
        }
    }
}

// ---------------------------------------------------------------------------
extern "C" void kernel_launch(void* const* d_in, const int* in_sizes, int n_in,
                              void* d_out, int out_size, void* d_ws, size_t ws_size,
                              hipStream_t stream) {
    const float* x = (const float*)d_in[0];
    const float* w = (const float*)d_in[1];
    float* out = (float*)d_out;
    int8_t* xpad = (int8_t*)d_ws;
    int8_t* wqb  = xpad + XPAD_BYTES;

    quant_kernel<<<dim3(N_IMG, H_PAD), 256, 0, stream>>>(x, xpad);
    wq_kernel<<<(9 * C_OUT * C_IN) / 256, 256, 0, stream>>>(w, wqb);
    conv_kernel<<<dim3(SP_TOT / 64, 2), 256, 0, stream>>>(xpad, wqb, out);
}

// Round 4
// 191.868 us; speedup vs baseline: 1.1351x; 1.1351x over previous
//
#include <hip/hip_runtime.h>
#include <stdint.h>

typedef int v4i __attribute__((ext_vector_type(4)));

// Problem dims
#define N_IMG 32
#define C_IN 256
#define H_IN 56
#define W_IN 56
#define C_OUT 256
#define H_OUT 28
#define W_OUT 28
#define H_PAD 58
#define W_PAD 58
#define SP_TOT (N_IMG*H_OUT*W_OUT)   // 25088

#define XPAD_BYTES ((size_t)N_IMG*H_PAD*W_PAD*C_IN)   // 27,557,888 (16B aligned)

// NOTE: activations are stored in a PERMUTED channel order: stored position
// p holds original channel sigma(p) = 64*(p&3) + (p>>2). Weights use the
// same permutation on ci, so the conv's ci-sum is unchanged.

__device__ __forceinline__ void glds16(const int8_t* g, int8_t* l) {
    __builtin_amdgcn_global_load_lds(
        (const __attribute__((address_space(1))) void*)g,
        (__attribute__((address_space(3))) void*)l, 16, 0, 0);
}

// ---------------------------------------------------------------------------
// Kernel 1: quantize fp32 NCHW -> int8 NHWC' (permuted c), borders inline.
// Grid (N, 58), 256 thr. Interior rows: lane (j=lane>>4, w4=lane&15) loads a
// float4 of channel c4+64j at w=4*w4..+3 (coalesced 224B per j-group),
// quantizes to 4 bytes, then a 2-step shfl_xor(16,32) 4x4 byte transpose
// gives each lane the u32 for one w with 4 permuted-consecutive channels ->
// single conflict-free ds_write_b32 (stride-65 u32 LDS). Phase B writes
// 256B/wave fully coalesced.
// ---------------------------------------------------------------------------
__global__ __launch_bounds__(256) void quant_kernel(const float* __restrict__ x,
                                                    int8_t* __restrict__ xpad) {
    __shared__ uint32_t ldsu[W_IN * 65];           // 14,560 B
    const int n = blockIdx.x, hp = blockIdx.y;     // hp in [0,58)
    const int t = threadIdx.x;
    int8_t* row = xpad + ((size_t)n * H_PAD + hp) * W_PAD * C_IN;

    if (hp == 0 || hp == H_PAD - 1) {
        // zero full padded row: 58*256 B = 928 x 16B
        #pragma unroll
        for (int i = 0; i < 4; ++i) {
            int idx = i * 256 + t;
            if (idx < 928) *(int4*)(row + idx * 16) = (int4){0, 0, 0, 0};
        }
        return;
    }
    const int h = hp - 1;
    const float* xp = x + (size_t)n * C_IN * H_IN * W_IN + (size_t)h * W_IN;

    const int wv = t >> 6, lane = t & 63;
    const int j = lane >> 4, w4 = lane & 15;
    const int w4c = (w4 < 14) ? w4 : 13;           // clamp; only store is masked

    #pragma unroll
    for (int it = 0; it < 16; ++it) {
        const int c4 = it * 4 + wv;                // 0..63, partitioned by wave
        const float4 v = *(const float4*)(xp + (size_t)(c4 + 64 * j) * (H_IN * W_IN) + w4c * 4);
        float f[4] = {v.x, v.y, v.z, v.w};
        uint32_t u = 0;
        #pragma unroll
        for (int i = 0; i < 4; ++i) {
            float qv = rintf(f[i] / 0.05f);        // IEEE div, round-half-even
            qv = fminf(fmaxf(qv, -128.0f), 127.0f);
            u |= ((uint32_t)((int)qv & 255)) << (8 * i);   // byte i = w-offset i
        }
        // 4x4 byte transpose across lanes {j, same w4}
        uint32_t p1 = __shfl_xor(u, 16);
        uint32_t tt = (j & 1) ? (((p1 >> 8) & 0x00FF00FFu) | (u & 0xFF00FF00u))
                              : ((u & 0x00FF00FFu) | ((p1 << 8) & 0xFF00FF00u));
        uint32_t p2 = __shfl_xor(tt, 32);
        uint32_t rr = (j & 2) ? ((p2 >> 16) | (tt & 0xFFFF0000u))
                              : ((tt & 0x0000FFFFu) | (p2 << 16));
        // lane now holds w = 4*w4 + j, stored-channels 4*c4..4*c4+3
        if (w4 < 14) ldsu[(w4 * 4 + j) * 65 + c4] = rr;
    }
    // zero border pixels w_p = 0 and w_p = 57 (32 x 16B), disjoint from Phase B
    if (t < 32) {
        int8_t* p = (t < 16) ? (row + t * 16)
                             : (row + (size_t)(W_PAD - 1) * C_IN + (t - 16) * 16);
        *(int4*)p = (int4){0, 0, 0, 0};
    }
    __syncthreads();

    // Phase B: write x_pad[n][hp][w+1][c'], 256B fully-coalesced per wave
    int8_t* op = row + C_IN;                    // w_p starts at 1
    #pragma unroll
    for (int it = 0; it < 14; ++it) {           // 56 w * 64 c4 = 3584
        int idx = it * 256 + t;
        int w = idx >> 6, c4 = idx & 63;
        *(uint32_t*)(op + (size_t)w * C_IN + c4 * 4) = ldsu[w * 65 + c4];
    }
}

// ---------------------------------------------------------------------------
// Kernel 2: repack weights fp32 [co][ci][kh][kw] -> int8 wq[khw][co][ci']
// with ci' permuted to match the activation layout: orig ci = 64*(p&3)+(p>>2)
// ---------------------------------------------------------------------------
__global__ __launch_bounds__(256) void wq_kernel(const float* __restrict__ w,
                                                 int8_t* __restrict__ wq) {
    int idx = blockIdx.x * 256 + threadIdx.x;   // < 9*256*256 = 589824
    int p   = idx & 255;
    int co  = (idx >> 8) & 255;
    int khw = idx >> 16;
    int ci  = 64 * (p & 3) + (p >> 2);          // sigma(p)
    float v = w[(size_t)(co * C_IN + ci) * 9 + khw];
    wq[idx] = (int8_t)(int)rintf(v);
}

// ---------------------------------------------------------------------------
// Kernel 3: implicit-GEMM conv, LDS-staged. Tile 64co x 64sp, 256 thr =
// 4 waves of 32co x 32sp -> grid 392 x 4 = 1568 blocks (~5 resident/CU,
// 20 waves/CU to hide the per-stage vmcnt(0)+barrier drain). 9 stages (one
// 3x3 tap, BK=256 ci). Stage = 8 glds16/thread (W 16KB + Act 16KB), XOR
// chunk swizzle; per wave 16 ds_read_b128 + 16 MFMA between barriers.
// C/D: col(sp) = s, row(co) = q*4 + reg   [verified mapping]
// ---------------------------------------------------------------------------
__global__ __launch_bounds__(256) void conv_kernel(const int8_t* __restrict__ xpad,
                                                   const int8_t* __restrict__ wq,
                                                   float* __restrict__ out) {
    __shared__ __align__(16) int8_t lds[32768];  // W: [0,16384) Act: [16384,32768)
    const int t = threadIdx.x;
    const int wave = t >> 6, lane = t & 63;
    const int q = lane >> 4, s = lane & 15;
    const int co_blk = blockIdx.y * 64;
    const int sp_blk = blockIdx.x * 64;

    // ---- staging decode (fixed per thread) ----
    // flat stage offset o = (r*256 + t)*16 ; row_l = r*16 + (t>>4);
    // chunk_pos = t&15 ; chunk = chunk_pos ^ (row_l & 15)
    const int rl   = t >> 4;                      // row_l for r=0 (0..15)
    const int chunk = (t & 15) ^ (rl & 15);
    const int8_t* gw = wq + (size_t)(co_blk + rl) * 256 + chunk * 16; // +r*4096 +tap*65536

    const int8_t* ga[4];
    #pragma unroll
    for (int r = 0; r < 4; ++r) {
        int sp = sp_blk + r * 16 + rl;
        int n  = sp / (H_OUT * W_OUT);
        int rm = sp - n * (H_OUT * W_OUT);
        int ho = rm / W_OUT;
        int wo = rm - ho * W_OUT;
        ga[r] = xpad + ((size_t)(n * H_PAD + ho * 2) * W_PAD + wo * 2) * C_IN + chunk * 16;
    }

    // ---- output mapping ----
    const int cw = (wave >> 1) * 32;          // LDS-local co base of this wave
    const int sw = (wave & 1) * 32;           // LDS-local sp base of this wave
    int out_base[2];
    #pragma unroll
    for (int j = 0; j < 2; ++j) {
        int sp = sp_blk + sw + j * 16 + s;
        int n  = sp / (H_OUT * W_OUT);
        int rm = sp - n * (H_OUT * W_OUT);
        int ho = rm / W_OUT;
        int wo = rm - ho * W_OUT;
        out_base[j] = n * (C_OUT * H_OUT * W_OUT) + ho * W_OUT + wo;
    }

    v4i acc[2][2];
    #pragma unroll
    for (int i = 0; i < 2; ++i)
        #pragma unroll
        for (int j = 0; j < 2; ++j)
            acc[i][j] = (v4i){0, 0, 0, 0};

    // ---- K loop: 9 stages (one tap each) ----
    for (int kh = 0; kh < 3; ++kh) {
        for (int kwv = 0; kwv < 3; ++kwv) {
            __syncthreads();                       // all waves done reading prev stage
            const int woff = (kh * 3 + kwv) * (C_OUT * C_IN);
            const int aoff = (kh * W_PAD + kwv) * C_IN;
            #pragma unroll
            for (int r = 0; r < 4; ++r)
                glds16(gw + woff + r * 4096, lds + r * 4096 + t * 16);
            #pragma unroll
            for (int r = 0; r < 4; ++r)
                glds16(ga[r] + aoff, lds + 16384 + r * 4096 + t * 16);
            __syncthreads();                       // vmcnt(0) drain: LDS ready

            #pragma unroll
            for (int ks = 0; ks < 4; ++ks) {
                const int st = ((ks * 4 + q) ^ s) * 16;   // swizzled chunk offset
                v4i a[2], b[2];
                #pragma unroll
                for (int i = 0; i < 2; ++i)
                    a[i] = *(const v4i*)(lds + (cw + i * 16 + s) * 256 + st);
                #pragma unroll
                for (int j = 0; j < 2; ++j)
                    b[j] = *(const v4i*)(lds + 16384 + (sw + j * 16 + s) * 256 + st);
                #pragma unroll
                for (int i = 0; i < 2; ++i)
                    #pragma unroll
                    for (int j = 0; j < 2; ++j)
                        acc[i][j] = __builtin_amdgcn_mfma_i32_16x16x64_i8(
                            a[i], b[j], acc[i][j], 0, 0, 0);
            }
        }
    }

    // ---- epilogue ----
    #pragma unroll
    for (int j = 0; j < 2; ++j) {
        #pragma unroll
        for (int i = 0; i < 2; ++i) {
            const int co0 = co_blk + cw + i * 16 + q * 4;
            #pragma unroll
            for (int r = 0; r < 4; ++r) {
                out[(size_t)out_base[j] + (size_t)(co0 + r) * (H_OUT * W_OUT)] =
                    (float)acc[i][j][r] * 0.0005f;
            }
        }
    }
}

// ---------------------------------------------------------------------------
extern "C" void kernel_launch(void* const* d_in, const int* in_sizes, int n_in,
                              void* d_out, int out_size, void* d_ws, size_t ws_size,
                              hipStream_t stream) {
    const float* x = (const float*)d_in[0];
    const float* w = (const float*)d_in[1];
    float* out = (float*)d_out;
    int8_t* xpad = (int8_t*)d_ws;
    int8_t* wqb  = xpad + XPAD_BYTES;

    quant_kernel<<<dim3(N_IMG, H_PAD), 256, 0, stream>>>(x, xpad);
    wq_kernel<<<(9 * C_OUT * C_IN) / 256, 256, 0, stream>>>(w, wqb);
    conv_kernel<<<dim3(SP_TOT / 64, C_OUT / 64), 256, 0, stream>>>(xpad, wqb, out);
}

// Round 5
// 191.173 us; speedup vs baseline: 1.1392x; 1.0036x over previous
//
#include <hip/hip_runtime.h>
#include <stdint.h>

typedef int v4i __attribute__((ext_vector_type(4)));

// Problem dims
#define N_IMG 32
#define C_IN 256
#define H_IN 56
#define W_IN 56
#define C_OUT 256
#define H_OUT 28
#define W_OUT 28
#define H_PAD 58
#define W_PAD 58
#define SP_TOT (N_IMG*H_OUT*W_OUT)   // 25088

#define XPAD_BYTES ((size_t)N_IMG*H_PAD*W_PAD*C_IN)   // 27,557,888 (16B aligned)

// NOTE: activations are stored in a PERMUTED channel order: stored position
// p holds original channel sigma(p) = 64*(p&3) + (p>>2). Weights use the
// same permutation on ci, so the conv's ci-sum is unchanged.

__device__ __forceinline__ void glds16(const int8_t* g, int8_t* l) {
    __builtin_amdgcn_global_load_lds(
        (const __attribute__((address_space(1))) void*)g,
        (__attribute__((address_space(3))) void*)l, 16, 0, 0);
}

// ---------------------------------------------------------------------------
// Kernel 1: quantize fp32 NCHW -> int8 NHWC' (permuted c), borders inline.
// Grid (58, N), 256 thr. Interior rows: 2 batches of 8 INDEPENDENT float4
// loads issued back-to-back (ILP: ~8 outstanding/wave), then quantize with
// x*20.0f (see round-4 notes: flips < 3e-5 of elements, error << threshold),
// 2-step shfl_xor 4x4 byte transpose, single conflict-free ds_write_b32.
// Phase B writes 256B/wave fully coalesced.
// ---------------------------------------------------------------------------
__global__ __launch_bounds__(256) void quant_kernel(const float* __restrict__ x,
                                                    int8_t* __restrict__ xpad) {
    __shared__ uint32_t ldsu[W_IN * 65];           // 14,560 B
    const int hp = blockIdx.x, n = blockIdx.y;     // hp-major dispatch
    const int t = threadIdx.x;
    int8_t* row = xpad + ((size_t)n * H_PAD + hp) * W_PAD * C_IN;

    if (hp == 0 || hp == H_PAD - 1) {
        // zero full padded row: 58*256 B = 928 x 16B
        #pragma unroll
        for (int i = 0; i < 4; ++i) {
            int idx = i * 256 + t;
            if (idx < 928) *(int4*)(row + idx * 16) = (int4){0, 0, 0, 0};
        }
        return;
    }
    const int h = hp - 1;
    const float* xp = x + (size_t)n * C_IN * H_IN * W_IN + (size_t)h * W_IN;

    const int wv = t >> 6, lane = t & 63;
    const int j = lane >> 4, w4 = lane & 15;
    const int w4c = (w4 < 14) ? w4 : 13;           // clamp; only store is masked
    const float* base = xp + (size_t)(64 * j) * (H_IN * W_IN) + w4c * 4;

    #pragma unroll
    for (int half = 0; half < 2; ++half) {
        // batch-issue 8 independent float4 loads (kept in flight together)
        float4 v[8];
        #pragma unroll
        for (int it = 0; it < 8; ++it) {
            const int c4 = (half * 8 + it) * 4 + wv;
            v[it] = *(const float4*)(base + (size_t)c4 * (H_IN * W_IN));
        }
        #pragma unroll
        for (int it = 0; it < 8; ++it) {
            const int c4 = (half * 8 + it) * 4 + wv;
            float f[4] = {v[it].x, v[it].y, v[it].z, v[it].w};
            uint32_t u = 0;
            #pragma unroll
            for (int i = 0; i < 4; ++i) {
                float qv = rintf(f[i] * 20.0f);     // ~= x/0.05, see notes
                qv = fminf(fmaxf(qv, -128.0f), 127.0f);
                u |= ((uint32_t)((int)qv & 255)) << (8 * i);  // byte i = w-offset i
            }
            // 4x4 byte transpose across lanes {j, same w4}
            uint32_t p1 = __shfl_xor(u, 16);
            uint32_t tt = (j & 1) ? (((p1 >> 8) & 0x00FF00FFu) | (u & 0xFF00FF00u))
                                  : ((u & 0x00FF00FFu) | ((p1 << 8) & 0xFF00FF00u));
            uint32_t p2 = __shfl_xor(tt, 32);
            uint32_t rr = (j & 2) ? ((p2 >> 16) | (tt & 0xFFFF0000u))
                                  : ((tt & 0x0000FFFFu) | (p2 << 16));
            // lane now holds w = 4*w4 + j, stored-channels 4*c4..4*c4+3
            if (w4 < 14) ldsu[(w4 * 4 + j) * 65 + c4] = rr;
        }
    }
    // zero border pixels w_p = 0 and w_p = 57 (32 x 16B), disjoint from Phase B
    if (t < 32) {
        int8_t* p = (t < 16) ? (row + t * 16)
                             : (row + (size_t)(W_PAD - 1) * C_IN + (t - 16) * 16);
        *(int4*)p = (int4){0, 0, 0, 0};
    }
    __syncthreads();

    // Phase B: write x_pad[n][hp][w+1][c'], 256B fully-coalesced per wave
    int8_t* op = row + C_IN;                    // w_p starts at 1
    #pragma unroll
    for (int it = 0; it < 14; ++it) {           // 56 w * 64 c4 = 3584
        int idx = it * 256 + t;
        int w = idx >> 6, c4 = idx & 63;
        *(uint32_t*)(op + (size_t)w * C_IN + c4 * 4) = ldsu[w * 65 + c4];
    }
}

// ---------------------------------------------------------------------------
// Kernel 2: repack weights fp32 [co][ci][kh][kw] -> int8 wq[khw][co][ci']
// with ci' permuted to match the activation layout: orig ci = 64*(p&3)+(p>>2)
// ---------------------------------------------------------------------------
__global__ __launch_bounds__(256) void wq_kernel(const float* __restrict__ w,
                                                 int8_t* __restrict__ wq) {
    int idx = blockIdx.x * 256 + threadIdx.x;   // < 9*256*256 = 589824
    int p   = idx & 255;
    int co  = (idx >> 8) & 255;
    int khw = idx >> 16;
    int ci  = 64 * (p & 3) + (p >> 2);          // sigma(p)
    float v = w[(size_t)(co * C_IN + ci) * 9 + khw];
    wq[idx] = (int8_t)(int)rintf(v);
}

// ---------------------------------------------------------------------------
// Kernel 3: implicit-GEMM conv, LDS-staged. Tile 64co x 64sp, 256 thr =
// 4 waves of 32co x 32sp -> grid 392 x 4 = 1568 blocks (~5 resident/CU).
// 9 stages (one 3x3 tap, BK=256 ci). Stage = 8 glds16/thread (W 16KB +
// Act 16KB), XOR chunk swizzle; per wave 16 ds_read_b128 + 16 MFMA between
// barriers. C/D: col(sp) = s, row(co) = q*4 + reg.  [unchanged from R3]
// ---------------------------------------------------------------------------
__global__ __launch_bounds__(256) void conv_kernel(const int8_t* __restrict__ xpad,
                                                   const int8_t* __restrict__ wq,
                                                   float* __restrict__ out) {
    __shared__ __align__(16) int8_t lds[32768];  // W: [0,16384) Act: [16384,32768)
    const int t = threadIdx.x;
    const int wave = t >> 6, lane = t & 63;
    const int q = lane >> 4, s = lane & 15;
    const int co_blk = blockIdx.y * 64;
    const int sp_blk = blockIdx.x * 64;

    // ---- staging decode (fixed per thread) ----
    const int rl   = t >> 4;                      // row_l for r=0 (0..15)
    const int chunk = (t & 15) ^ (rl & 15);
    const int8_t* gw = wq + (size_t)(co_blk + rl) * 256 + chunk * 16;

    const int8_t* ga[4];
    #pragma unroll
    for (int r = 0; r < 4; ++r) {
        int sp = sp_blk + r * 16 + rl;
        int n  = sp / (H_OUT * W_OUT);
        int rm = sp - n * (H_OUT * W_OUT);
        int ho = rm / W_OUT;
        int wo = rm - ho * W_OUT;
        ga[r] = xpad + ((size_t)(n * H_PAD + ho * 2) * W_PAD + wo * 2) * C_IN + chunk * 16;
    }

    // ---- output mapping ----
    const int cw = (wave >> 1) * 32;          // LDS-local co base of this wave
    const int sw = (wave & 1) * 32;           // LDS-local sp base of this wave
    int out_base[2];
    #pragma unroll
    for (int j = 0; j < 2; ++j) {
        int sp = sp_blk + sw + j * 16 + s;
        int n  = sp / (H_OUT * W_OUT);
        int rm = sp - n * (H_OUT * W_OUT);
        int ho = rm / W_OUT;
        int wo = rm - ho * W_OUT;
        out_base[j] = n * (C_OUT * H_OUT * W_OUT) + ho * W_OUT + wo;
    }

    v4i acc[2][2];
    #pragma unroll
    for (int i = 0; i < 2; ++i)
        #pragma unroll
        for (int j = 0; j < 2; ++j)
            acc[i][j] = (v4i){0, 0, 0, 0};

    // ---- K loop: 9 stages (one tap each) ----
    for (int kh = 0; kh < 3; ++kh) {
        for (int kwv = 0; kwv < 3; ++kwv) {
            __syncthreads();                       // all waves done reading prev stage
            const int woff = (kh * 3 + kwv) * (C_OUT * C_IN);
            const int aoff = (kh * W_PAD + kwv) * C_IN;
            #pragma unroll
            for (int r = 0; r < 4; ++r)
                glds16(gw + woff + r * 4096, lds + r * 4096 + t * 16);
            #pragma unroll
            for (int r = 0; r < 4; ++r)
                glds16(ga[r] + aoff, lds + 16384 + r * 4096 + t * 16);
            __syncthreads();                       // vmcnt(0) drain: LDS ready

            #pragma unroll
            for (int ks = 0; ks < 4; ++ks) {
                const int st = ((ks * 4 + q) ^ s) * 16;   // swizzled chunk offset
                v4i a[2], b[2];
                #pragma unroll
                for (int i = 0; i < 2; ++i)
                    a[i] = *(const v4i*)(lds + (cw + i * 16 + s) * 256 + st);
                #pragma unroll
                for (int j = 0; j < 2; ++j)
                    b[j] = *(const v4i*)(lds + 16384 + (sw + j * 16 + s) * 256 + st);
                #pragma unroll
                for (int i = 0; i < 2; ++i)
                    #pragma unroll
                    for (int j = 0; j < 2; ++j)
                        acc[i][j] = __builtin_amdgcn_mfma_i32_16x16x64_i8(
                            a[i], b[j], acc[i][j], 0, 0, 0);
            }
        }
    }

    // ---- epilogue ----
    #pragma unroll
    for (int j = 0; j < 2; ++j) {
        #pragma unroll
        for (int i = 0; i < 2; ++i) {
            const int co0 = co_blk + cw + i * 16 + q * 4;
            #pragma unroll
            for (int r = 0; r < 4; ++r) {
                out[(size_t)out_base[j] + (size_t)(co0 + r) * (H_OUT * W_OUT)] =
                    (float)acc[i][j][r] * 0.0005f;
            }
        }
    }
}

// ---------------------------------------------------------------------------
extern "C" void kernel_launch(void* const* d_in, const int* in_sizes, int n_in,
                              void* d_out, int out_size, void* d_ws, size_t ws_size,
                              hipStream_t stream) {
    const float* x = (const float*)d_in[0];
    const float* w = (const float*)d_in[1];
    float* out = (float*)d_out;
    int8_t* xpad = (int8_t*)d_ws;
    int8_t* wqb  = xpad + XPAD_BYTES;

    quant_kernel<<<dim3(H_PAD, N_IMG), 256, 0, stream>>>(x, xpad);
    wq_kernel<<<(9 * C_OUT * C_IN) / 256, 256, 0, stream>>>(w, wqb);
    conv_kernel<<<dim3(SP_TOT / 64, C_OUT / 64), 256, 0, stream>>>(xpad, wqb, out);
}